// Round 5
// baseline (11431.219 us; speedup 1.0000x reference)
//
#include <hip/hip_runtime.h>
#include <hip/hip_bf16.h>
#include <stdint.h>

#define BATCH 4096
#define TT    80
#define EMB   100
#define UNITS 512
#define K0P   128
#define NBLK  512

typedef unsigned short ushort;
typedef unsigned char uchar;
typedef __bf16 bf16x8 __attribute__((ext_vector_type(8)));
typedef float f32x4 __attribute__((ext_vector_type(4)));
typedef uint32_t u32x4 __attribute__((ext_vector_type(4)));

// ---------------- threefry2x32 (JAX partitionable mode, verified r1) ------
__device__ __forceinline__ uint32_t rotl32(uint32_t x, uint32_t r) {
  return (x << r) | (x >> (32u - r));
}
__device__ __forceinline__ void tf_round4(uint32_t& x0, uint32_t& x1,
                                          int r0, int r1, int r2, int r3) {
  x0 += x1; x1 = rotl32(x1, r0); x1 ^= x0;
  x0 += x1; x1 = rotl32(x1, r1); x1 ^= x0;
  x0 += x1; x1 = rotl32(x1, r2); x1 ^= x0;
  x0 += x1; x1 = rotl32(x1, r3); x1 ^= x0;
}
__device__ __forceinline__ void tf2x32(uint32_t k0, uint32_t k1,
                                       uint32_t x0, uint32_t x1,
                                       uint32_t& y0, uint32_t& y1) {
  uint32_t k2 = k0 ^ k1 ^ 0x1BD11BDAu;
  x0 += k0; x1 += k1;
  tf_round4(x0, x1, 13, 15, 26, 6);  x0 += k1; x1 += k2 + 1u;
  tf_round4(x0, x1, 17, 29, 16, 24); x0 += k2; x1 += k0 + 2u;
  tf_round4(x0, x1, 13, 15, 26, 6);  x0 += k0; x1 += k1 + 3u;
  tf_round4(x0, x1, 17, 29, 16, 24); x0 += k1; x1 += k2 + 4u;
  tf_round4(x0, x1, 13, 15, 26, 6);  x0 += k2; x1 += k0 + 5u;
  y0 = x0; y1 = x1;
}
__device__ __forceinline__ int keepbit(uint32_t u) {
  float f = __uint_as_float((u >> 9) | 0x3F800000u) - 1.0f;
  return f < 0.8f ? 1 : 0;
}
__device__ __forceinline__ ushort f2bf(float f) {
  uint32_t u = __float_as_uint(f);
  uint32_t r = (u + 0x7FFFu + ((u >> 16) & 1u)) >> 16;
  return (ushort)r;
}
__device__ __forceinline__ float bf2f(ushort u) {
  return __uint_as_float(((uint32_t)u) << 16);
}

// ---------------- byte masks: 0xFF = keep, 0x00 = drop --------------------
__global__ __launch_bounds__(256) void masksB(uchar* __restrict__ m0B,
                                              uchar* __restrict__ m1B) {
  uint32_t k0a, k0b, k1a, k1b;
  tf2x32(0u, 42u, 0u, 0u, k0a, k0b);
  tf2x32(0u, 42u, 0u, 1u, k1a, k1b);
  const int T0 = 4 * BATCH * K0P;
  const int T1 = 4 * BATCH * UNITS;
  for (int i = blockIdx.x * blockDim.x + threadIdx.x; i < T0 + T1;
       i += gridDim.x * blockDim.x) {
    if (i < T0) {
      const int g = i >> 19, b = (i >> 7) & 4095, k = i & 127;
      uchar v = 0;
      if (k < EMB) {
        uint32_t y0, y1;
        tf2x32(k0a, k0b, 0u, (uint32_t)(g * (BATCH * EMB) + b * EMB + k), y0, y1);
        v = keepbit(y0 ^ y1) ? 0xFFu : 0u;
      }
      m0B[i] = v;
    } else {
      const int j = i - T0;
      const int g = j >> 21, b = (j >> 9) & 4095, k = j & 511;
      uint32_t y0, y1;
      tf2x32(k1a, k1b, 0u, (uint32_t)(g * (BATCH * UNITS) + b * UNITS + k), y0, y1);
      m1B[j] = keepbit(y0 ^ y1) ? 0xFFu : 0u;
    }
  }
}

// weight convert+transpose+scale: src[K][2048] f32 -> dst[2048][Kpad] bf16
__global__ __launch_bounds__(256) void convT(const float* __restrict__ src,
                                             ushort* __restrict__ dst,
                                             int Ksrc, int Kpad, float scale) {
  __shared__ float t[32][33];
  const int n0 = blockIdx.x * 32, kk0 = blockIdx.y * 32;
  const int tx = threadIdx.x & 31, ty = threadIdx.x >> 5;
#pragma unroll
  for (int r = ty; r < 32; r += 8) {
    const int k = kk0 + r;
    t[r][tx] = (k < Ksrc) ? src[(size_t)k * 2048 + n0 + tx] : 0.f;
  }
  __syncthreads();
#pragma unroll
  for (int r = ty; r < 32; r += 8)
    dst[(size_t)(n0 + r) * Kpad + kk0 + tx] = f2bf(scale * t[tx][r]);
}

// initial X prep: step 0 -> XA, step 1 -> XB
__global__ __launch_bounds__(256) void xprep2(const int* __restrict__ inputs,
                                              const float* __restrict__ embed,
                                              ushort* __restrict__ XA,
                                              ushort* __restrict__ XB) {
  const int i = blockIdx.x * 256 + threadIdx.x;  // 2 * 65536
  const int s = i >> 16, r = i & 65535;
  const int b = r >> 4, k = (r & 15) * 8;
  ushort* X = s ? XB : XA;
  const int idx = inputs[b * TT + s];
  ushort v[8];
#pragma unroll
  for (int j = 0; j < 8; j++) {
    const int kk = k + j;
    float f = 0.f;
    if (kk < EMB) f = embed[(size_t)idx * EMB + kk];
    v[j] = f2bf(f);
  }
  *(bf16x8*)(X + (size_t)b * K0P + k) = *(bf16x8*)v;
}

__device__ __forceinline__ void gload16(const void* g, void* l) {
  __builtin_amdgcn_global_load_lds(
      (const __attribute__((address_space(1))) unsigned int*)g,
      (__attribute__((address_space(3))) unsigned int*)l, 16, 0, 0);
}

// ---------------- one GEMM segment (K-loop) over acc ----------------------
template <bool MASKED>
__device__ __forceinline__ void gemm_seg(
    const ushort* __restrict__ A, int K, const ushort* __restrict__ Bw,
    const uchar* __restrict__ mB, int bm0, int bh0, int tid,
    ushort* As, ushort* Bs, f32x4 acc[4][8]) {
  const int w = tid >> 6, l = tid & 63;
  const int wr = w >> 1, wc = w & 1;
  const int fr = l & 15, kq = l >> 4;
  const int srow = l >> 2, schunk = (l & 3) * 8;

#pragma unroll 1
  for (int k0 = 0; k0 < K; k0 += 32) {
#pragma unroll
    for (int c2 = 0; c2 < 2; c2++) {
      const int rt = w + c2 * 4;
      gload16(A + (size_t)(bm0 + rt * 16 + srow) * K + k0 + schunk,
              As + rt * 512);
    }
#pragma unroll
    for (int c2 = 0; c2 < 4; c2++) {
      const int ct = w * 4 + c2;
      const int col = ct * 16 + srow;
      const int nrow = (col >> 6) * 512 + bh0 + (col & 63);
      gload16(Bw + (size_t)nrow * K + k0 + schunk, Bs + ct * 512);
    }
    __syncthreads();
    u32x4 af[4];
#pragma unroll
    for (int fi = 0; fi < 4; fi++)
      af[fi] = *(const u32x4*)&As[(wr * 64 + fi * 16 + fr) * 32 + kq * 8];
#pragma unroll
    for (int g = 0; g < 4; g++) {
      const bf16x8 b0v =
          *(const bf16x8*)&Bs[((g * 4 + wc * 2 + 0) * 16 + fr) * 32 + kq * 8];
      const bf16x8 b1v =
          *(const bf16x8*)&Bs[((g * 4 + wc * 2 + 1) * 16 + fr) * 32 + kq * 8];
#pragma unroll
      for (int fi = 0; fi < 4; fi++) {
        u32x4 ua = af[fi];
        if (MASKED) {
          const int row = bm0 + wr * 64 + fi * 16 + fr;
          const uint2 m =
              *(const uint2*)(mB + (size_t)(g * BATCH + row) * K + k0 + kq * 8);
          ua.x &= __builtin_amdgcn_perm(m.x, m.x, 0x01010000u);
          ua.y &= __builtin_amdgcn_perm(m.x, m.x, 0x03030202u);
          ua.z &= __builtin_amdgcn_perm(m.y, m.y, 0x01010000u);
          ua.w &= __builtin_amdgcn_perm(m.y, m.y, 0x03030202u);
        }
        const bf16x8 a = __builtin_bit_cast(bf16x8, ua);
        acc[fi][g * 2 + 0] = __builtin_amdgcn_mfma_f32_16x16x32_bf16(
            a, b0v, acc[fi][g * 2 + 0], 0, 0, 0);
        acc[fi][g * 2 + 1] = __builtin_amdgcn_mfma_f32_16x16x32_bf16(
            a, b1v, acc[fi][g * 2 + 1], 0, 0, 0);
      }
    }
    __syncthreads();
  }
}

// grid barrier: release-fence (L2 writeback), arrive, spin relaxed, acquire
__device__ __forceinline__ void gbar(unsigned* cnt, unsigned target) {
  __syncthreads();
  if (threadIdx.x == 0) {
    __builtin_amdgcn_fence(__ATOMIC_RELEASE, "agent");
    __hip_atomic_fetch_add(cnt, 1u, __ATOMIC_RELAXED, __HIP_MEMORY_SCOPE_AGENT);
    unsigned v;
    int it = 0;
    do {
      __builtin_amdgcn_s_sleep(2);
      v = __hip_atomic_load(cnt, __ATOMIC_RELAXED, __HIP_MEMORY_SCOPE_AGENT);
    } while (v < target && ++it < 10000000);
    __builtin_amdgcn_fence(__ATOMIC_ACQUIRE, "agent");
  }
  __syncthreads();
}

// ---------------- persistent LSTM: 81 phases, c-state in registers --------
__global__ __launch_bounds__(256, 2) void lstm_persist(
    const ushort* __restrict__ W0T, const ushort* __restrict__ U0T,
    const float* __restrict__ b0, const ushort* __restrict__ W1T,
    const ushort* __restrict__ U1T, const float* __restrict__ b1,
    const uchar* __restrict__ m0B, const uchar* __restrict__ m1B,
    ushort* __restrict__ h0A, ushort* __restrict__ h0B_,
    ushort* __restrict__ h1A, ushort* __restrict__ h1B_,
    ushort* __restrict__ XA, ushort* __restrict__ XB,
    const int* __restrict__ inputs, const float* __restrict__ embed,
    unsigned* __restrict__ barcnt) {
  __shared__ __align__(16) ushort smem[12288];
  const int bid = blockIdx.x, tid = threadIdx.x;
  // co-location: intended XCD = bid&7 hosts mblks 4x..4x+3, both layers,
  // all nblk -> h-panel producer/consumer traffic stays on one XCD (perf
  // only; correctness is carried by the gbar fences).
  const int x = bid & 7, j = bid >> 3;
  const bool isl1 = j & 1;
  const int mblk = x * 4 + ((j >> 1) & 3);
  const int nblk = j >> 3;
  const int bm0 = mblk * 128, bh0 = nblk * 64;
  const int w = tid >> 6, l = tid & 63;
  const int wr = w >> 1, wc = w & 1;
  const int fr = l & 15, kq = l >> 4;

  ushort* h0buf[2] = {h0A, h0B_};
  ushort* h1buf[2] = {h1A, h1B_};
  ushort* Xbuf[2] = {XA, XB};

  f32x4 cfr[8];
#pragma unroll
  for (int q = 0; q < 8; q++) cfr[q] = f32x4{0.f, 0.f, 0.f, 0.f};

  float bi[2], bfv[2], bg[2], bo[2];
  {
    const float* bias = isl1 ? b1 : b0;
#pragma unroll
    for (int hf = 0; hf < 2; hf++) {
      const int h = bh0 + wc * 32 + hf * 16 + fr;
      bi[hf] = bias[h];
      bfv[hf] = bias[512 + h];
      bg[hf] = bias[1024 + h];
      bo[hf] = bias[1536 + h];
    }
  }

#pragma unroll 1
  for (int ph = 0; ph <= 80; ph++) {
    const int p = ph & 1;
    const bool active = isl1 ? (ph >= 1) : (ph <= 79);
    if (active) {
      f32x4 acc[4][8] = {};
      if (isl1) {
        gemm_seg<true>(h0buf[p ^ 1], UNITS, W1T, m1B, bm0, bh0, tid, smem,
                       smem + 4096, acc);
        gemm_seg<false>(h1buf[p ^ 1], UNITS, U1T, nullptr, bm0, bh0, tid, smem,
                        smem + 4096, acc);
      } else {
        gemm_seg<true>(Xbuf[p], K0P, W0T, m0B, bm0, bh0, tid, smem,
                       smem + 4096, acc);
        gemm_seg<false>(h0buf[p ^ 1], UNITS, U0T, nullptr, bm0, bh0, tid, smem,
                        smem + 4096, acc);
      }
      ushort* hout = isl1 ? h1buf[p] : h0buf[p];
      // gates epilogue: c in registers, h transposed through LDS
#pragma unroll
      for (int fi = 0; fi < 4; fi++) {
#pragma unroll
        for (int hf = 0; hf < 2; hf++) {
#pragma unroll
          for (int jj = 0; jj < 4; jj++) {
            const float zi = acc[fi][0 + hf][jj] + bi[hf];
            const float zf = acc[fi][2 + hf][jj] + bfv[hf];
            const float zg = acc[fi][4 + hf][jj] + bg[hf];
            const float zo = acc[fi][6 + hf][jj] + bo[hf];
            const float iv = 1.f / (1.f + __expf(-zi));
            const float fv = 1.f / (1.f + __expf(-zf));
            const float gv = tanhf(zg);
            const float ov = 1.f / (1.f + __expf(-zo));
            const float cn = fv * cfr[fi * 2 + hf][jj] + iv * gv;
            cfr[fi * 2 + hf][jj] = cn;
            const float hn = ov * tanhf(cn);
            smem[(wr * 64 + fi * 16 + kq * 4 + jj) * 64 + wc * 32 + hf * 16 +
                 fr] = f2bf(hn);
          }
        }
      }
      __syncthreads();
#pragma unroll
      for (int c2 = 0; c2 < 4; c2++) {
        const int idx = c2 * 256 + tid;
        const int rloc = idx >> 3, hcol = (idx & 7) * 8;
        *(bf16x8*)(hout + (size_t)(bm0 + rloc) * UNITS + bh0 + hcol) =
            *(const bf16x8*)&smem[rloc * 64 + hcol];
      }
      // X prep for step ph+2 (l0 blocks, own rows only)
      if (!isl1 && ph + 2 <= 79) {
        const int r = tid >> 1, half = tid & 1;
        const int row = bm0 + r;
        const int idx = inputs[row * TT + ph + 2];
        ushort* dst = Xbuf[p] + (size_t)row * K0P + half * 64;
        const float* src = embed + (size_t)idx * EMB + half * 64;
#pragma unroll
        for (int kk = 0; kk < 64; kk += 8) {
          ushort v[8];
#pragma unroll
          for (int q2 = 0; q2 < 8; q2++) {
            const int col = half * 64 + kk + q2;
            float f = 0.f;
            if (col < EMB) f = src[kk + q2];
            v[q2] = f2bf(f);
          }
          *(bf16x8*)(dst + kk) = *(bf16x8*)v;
        }
      }
    }
    if (ph < 80) gbar(barcnt, (unsigned)(ph + 1) * (unsigned)NBLK);
  }
}

// ---------------- final projection ---------------------------------------
__global__ __launch_bounds__(256) void out_kernel(const ushort* __restrict__ h1b,
                                                  const float* __restrict__ Wout,
                                                  const float* __restrict__ bout,
                                                  float* __restrict__ out) {
  const int wid = (blockIdx.x * blockDim.x + threadIdx.x) >> 6;
  const int lane = threadIdx.x & 63;
  if (wid >= BATCH) return;
  const ushort* hr = h1b + (size_t)wid * UNITS;
  float s = 0.f;
#pragma unroll
  for (int j = 0; j < UNITS; j += 64) s += bf2f(hr[j + lane]) * Wout[j + lane];
  for (int off = 32; off; off >>= 1) s += __shfl_down(s, off, 64);
  if (lane == 0) out[wid] = 1.f / (1.f + __expf(-(s + bout[0])));
}

// --------------------------------------------------------------------------
extern "C" void kernel_launch(void* const* d_in, const int* in_sizes, int n_in,
                              void* d_out, int out_size, void* d_ws, size_t ws_size,
                              hipStream_t stream) {
  const int* inputs = (const int*)d_in[0];
  const float* embed = (const float*)d_in[1];
  const float* W0 = (const float*)d_in[2];
  const float* U0 = (const float*)d_in[3];
  const float* b0 = (const float*)d_in[4];
  const float* W1 = (const float*)d_in[5];
  const float* U1 = (const float*)d_in[6];
  const float* b1 = (const float*)d_in[7];
  const float* Wout = (const float*)d_in[8];
  const float* bout = (const float*)d_in[9];
  float* out = (float*)d_out;

  char* ws = (char*)d_ws;
  const size_t MB = 1 << 20;
  ushort* h0A  = (ushort*)(ws + 0 * MB);    // 4 MB
  ushort* h0B_ = (ushort*)(ws + 4 * MB);    // 4 MB (zero)
  ushort* h1A  = (ushort*)(ws + 8 * MB);    // 4 MB (zero)
  ushort* h1B_ = (ushort*)(ws + 12 * MB);   // 4 MB
  ushort* XA   = (ushort*)(ws + 16 * MB);   // 1 MB
  ushort* XB   = (ushort*)(ws + 17 * MB);   // 1 MB
  ushort* W0T  = (ushort*)(ws + 18 * MB);   // 0.5 MB [2048][128]
  ushort* U0T  = (ushort*)(ws + 19 * MB);   // 2 MB   [2048][512]
  ushort* W1T  = (ushort*)(ws + 21 * MB);   // 2 MB
  ushort* U1T  = (ushort*)(ws + 23 * MB);   // 2 MB
  uchar* m0B   = (uchar*)(ws + 25 * MB);    // 2 MB   [4][4096][128]
  uchar* m1B   = (uchar*)(ws + 27 * MB);    // 8 MB   [4][4096][512]
  unsigned* barcnt = (unsigned*)(ws + 35 * MB);

  hipMemsetAsync(ws + 4 * MB, 0, 8 * MB, stream);   // h0B_, h1A
  hipMemsetAsync(barcnt, 0, 4096, stream);

  masksB<<<8192, 256, 0, stream>>>(m0B, m1B);
  {
    dim3 g0(2048 / 32, K0P / 32);
    convT<<<g0, 256, 0, stream>>>(W0, W0T, EMB, K0P, 1.25f);
    dim3 g1(2048 / 32, UNITS / 32);
    convT<<<g1, 256, 0, stream>>>(U0, U0T, UNITS, UNITS, 1.0f);
    convT<<<g1, 256, 0, stream>>>(W1, W1T, UNITS, UNITS, 1.25f);
    convT<<<g1, 256, 0, stream>>>(U1, U1T, UNITS, UNITS, 1.0f);
  }
  xprep2<<<512, 256, 0, stream>>>(inputs, embed, XA, XB);

  lstm_persist<<<NBLK, 256, 0, stream>>>(W0T, U0T, b0, W1T, U1T, b1, m0B, m1B,
                                         h0A, h0B_, h1A, h1B_, XA, XB, inputs,
                                         embed, barcnt);

  // final h1 is h1buf[80 & 1] = h1A
  out_kernel<<<BATCH * 64 / 256, 256, 0, stream>>>(h1A, Wout, bout, out);
}